// Round 7
// baseline (873.522 us; speedup 1.0000x reference)
//
#include <hip/hip_runtime.h>

#define M_SZ 32768
#define N_SZ 4096
#define DEPTHS 4
#define SPLITKZ 8
#define KCHZ 512

typedef __attribute__((ext_vector_type(8))) short bh8;   // 8 bf16 MFMA frag
typedef __attribute__((ext_vector_type(4))) float f4;    // MFMA accumulator
typedef unsigned short u16;
typedef unsigned int u32;

#define SBAR() __builtin_amdgcn_s_barrier()
#define FENCE() asm volatile("" ::: "memory")
#define WAITV(n) asm volatile("s_waitcnt vmcnt(" #n ")" ::: "memory")
#define WAITVL(n) asm volatile("s_waitcnt vmcnt(" #n ") lgkmcnt(0)" ::: "memory")

__device__ __forceinline__ u16 f2bf(float f) {
  u32 u = __float_as_uint(f);
  u = (u + 0x7FFFu + ((u >> 16) & 1u)) >> 16;  // RNE
  return (u16)u;
}

__device__ __forceinline__ float fast_tanh(float x) {
  float ax = __builtin_fabsf(x);
  float e = __builtin_exp2f(ax * 2.8853900817779268f);  // e^(2|x|)
  float r = 1.0f - 2.0f * __builtin_amdgcn_rcpf(e + 1.0f);
  return __builtin_copysignf(r, x);
}

__device__ __forceinline__ void async16(const void* g, void* l) {
  __builtin_amdgcn_global_load_lds((const __attribute__((address_space(1))) u32*)g,
                                   (__attribute__((address_space(3))) u32*)l, 16, 0, 0);
}

// ---------------------------------------------------------------------------
// t0: sT[c][n] = self_act[n][c]  (64x64 tiles via LDS, both sides coalesced)
// ---------------------------------------------------------------------------
__global__ void t0_kernel(const float* __restrict__ in, float* __restrict__ sT) {
  __shared__ float tile[64 * 68];
  const int t = threadIdx.x;
  const int n0 = blockIdx.x * 64, c0 = blockIdx.y * 64;
#pragma unroll
  for (int j = 0; j < 4; ++j) {
    int row = j * 16 + (t >> 4), c4 = t & 15;
    float4 v = *(const float4*)(in + (size_t)(n0 + row) * 128 + c0 + c4 * 4);
    tile[row * 68 + c4 * 4 + 0] = v.x;
    tile[row * 68 + c4 * 4 + 1] = v.y;
    tile[row * 68 + c4 * 4 + 2] = v.z;
    tile[row * 68 + c4 * 4 + 3] = v.w;
  }
  __syncthreads();
#pragma unroll
  for (int j = 0; j < 4; ++j) {
    int cc = j * 16 + (t >> 4), r4 = t & 15;
    float4 v;
    v.x = tile[(r4 * 4 + 0) * 68 + cc];
    v.y = tile[(r4 * 4 + 1) * 68 + cc];
    v.z = tile[(r4 * 4 + 2) * 68 + cc];
    v.w = tile[(r4 * 4 + 3) * 68 + cc];
    *(float4*)(sT + (size_t)(c0 + cc) * 4096 + n0 + r4 * 4) = v;
  }
}

// ---------------------------------------------------------------------------
// k1: y_d[i][n] = sum_k sT[k][n] * Wd[i][k]  (write transposed bf16)
// ---------------------------------------------------------------------------
__global__ void k1_kernel(const float* __restrict__ sT, const float* __restrict__ Wd,
                          u16* __restrict__ Ytd, u32* __restrict__ cnt) {
  __shared__ float wlds[16 * 132];
  const int t = threadIdx.x;
  if (blockIdx.x == 0 && blockIdx.y == 0 && t < 64) cnt[t] = 0;
  const int n0 = blockIdx.x * 64, i0 = blockIdx.y * 16;
  const int iq = t & 15, ng = t >> 4;
  const int n = n0 + ng * 4;
#pragma unroll
  for (int j = 0; j < 2; ++j) {
    int li = j * 256 + t;
    int row = li >> 5, c4 = li & 31;
    float4 v = *(const float4*)(Wd + (i0 + row) * 128 + c4 * 4);
    *(float4*)(wlds + row * 132 + c4 * 4) = v;
  }
  __syncthreads();
  float acc[4] = {0.f, 0.f, 0.f, 0.f};
#pragma unroll 4
  for (int k4 = 0; k4 < 32; ++k4) {
    float4 wv = *(const float4*)(wlds + iq * 132 + k4 * 4);
#pragma unroll
    for (int j = 0; j < 4; ++j) {
      float4 sv = *(const float4*)(sT + (size_t)(k4 * 4 + j) * 4096 + n);
      float w = (j == 0) ? wv.x : (j == 1) ? wv.y : (j == 2) ? wv.z : wv.w;
      acc[0] = fmaf(w, sv.x, acc[0]);
      acc[1] = fmaf(w, sv.y, acc[1]);
      acc[2] = fmaf(w, sv.z, acc[2]);
      acc[3] = fmaf(w, sv.w, acc[3]);
    }
  }
  union { ushort4 v; u16 u[4]; } o;
#pragma unroll
  for (int j = 0; j < 4; ++j) o.u[j] = f2bf(acc[j]);
  *(ushort4*)(Ytd + (size_t)(i0 + iq) * 4096 + n) = o.v;
}

// ---------------------------------------------------------------------------
// k2: z = SK @ y_d, split-K 8 (grid 512 = 2 blocks/CU for stall overlap).
// tile 64n x 128i, K-chunk 512, K-step 64 (8 iters). Deterministic
// last-block finisher: fixed-order c-sum + bias + tanh -> s_out AND sT.
// ---------------------------------------------------------------------------
__global__ __launch_bounds__(512, 2) void k2_kernel(
    const float* __restrict__ SK, const u16* __restrict__ Ytd,
    float* __restrict__ Zp, u32* __restrict__ cnt,
    const float* __restrict__ s_src, float* __restrict__ s_out,
    float* __restrict__ sT, const float* __restrict__ bd) {
  __shared__ char smem[8192 + 2 * 16384];
  __shared__ u32 lastFlag;
  char* sA = smem;
  char* sB0 = smem + 8192;
  char* sB1 = smem + 8192 + 16384;
  const int t = threadIdx.x, lane = t & 63, wid = t >> 6;
  const int nb = blockIdx.x, c = blockIdx.y;
  const int n0 = nb * 64;
  const int kbz = c * KCHZ;
  const int wr = wid >> 1, wc = wid & 1;
  const int l15 = lane & 15, l4 = lane >> 4;

  const int arow = t >> 3, kseg8 = t & 7;
  const float4* agz = (const float4*)(SK + (size_t)(n0 + arow) * 4096 + kbz + kseg8 * 8);
  const int awoff = arow * 128 + ((kseg8 ^ (arow & 7)) << 4);

  int bcol[2], bgq[2], bldst[2];
#pragma unroll
  for (int j = 0; j < 2; ++j) {
    int G = j * 512 + t;
    bcol[j] = G >> 3;
    bgq[j] = (G & 7) ^ (bcol[j] & 7);
    bldst[j] = G * 16;
  }

  int aro, bro[4];
  {
    int row = wr * 16 + l15;
    aro = row * 128 + ((l4 ^ (row & 7)) << 4);
  }
#pragma unroll
  for (int n2 = 0; n2 < 4; ++n2) {
    int col = wc * 64 + n2 * 16 + l15;
    bro[n2] = col * 128 + ((l4 ^ (col & 7)) << 4);
  }

  f4 acc[4];
#pragma unroll
  for (int j = 0; j < 4; ++j) acc[j] = (f4){0.f, 0.f, 0.f, 0.f};

  float4 va0 = agz[0], va1 = agz[1];
  FENCE();
  async16(Ytd + (size_t)bcol[0] * 4096 + kbz + bgq[0] * 8, sB0 + bldst[0]);
  async16(Ytd + (size_t)bcol[1] * 4096 + kbz + bgq[1] * 8, sB0 + bldst[1]);
  FENCE();
  char* sBc = sB0;
  char* sBn = sB1;
  for (int k = 0; k < 7; ++k) {
    SBAR(); FENCE();
    WAITV(2);
    union { bh8 v; u16 u[8]; } p;
    p.u[0] = f2bf(va0.x); p.u[1] = f2bf(va0.y); p.u[2] = f2bf(va0.z); p.u[3] = f2bf(va0.w);
    p.u[4] = f2bf(va1.x); p.u[5] = f2bf(va1.y); p.u[6] = f2bf(va1.z); p.u[7] = f2bf(va1.w);
    *(bh8*)(sA + awoff) = p.v;
    FENCE();
    va0 = agz[(k + 1) * 16]; va1 = agz[(k + 1) * 16 + 1];
    FENCE();
    WAITVL(2);
    SBAR(); FENCE();
    async16(Ytd + (size_t)bcol[0] * 4096 + kbz + bgq[0] * 8 + (k + 1) * 64, sBn + bldst[0]);
    async16(Ytd + (size_t)bcol[1] * 4096 + kbz + bgq[1] * 8 + (k + 1) * 64, sBn + bldst[1]);
    FENCE();
#pragma unroll
    for (int kk = 0; kk < 2; ++kk) {
      bh8 a = *(const bh8*)(sA + (aro ^ (kk << 6)));
#pragma unroll
      for (int n2 = 0; n2 < 4; ++n2) {
        bh8 bb = *(const bh8*)(sBc + (bro[n2] ^ (kk << 6)));
        acc[n2] = __builtin_amdgcn_mfma_f32_16x16x32_bf16(a, bb, acc[n2], 0, 0, 0);
      }
    }
    char* tp = sBc; sBc = sBn; sBn = tp;
  }
  SBAR(); FENCE();
  WAITV(2);
  {
    union { bh8 v; u16 u[8]; } p;
    p.u[0] = f2bf(va0.x); p.u[1] = f2bf(va0.y); p.u[2] = f2bf(va0.z); p.u[3] = f2bf(va0.w);
    p.u[4] = f2bf(va1.x); p.u[5] = f2bf(va1.y); p.u[6] = f2bf(va1.z); p.u[7] = f2bf(va1.w);
    *(bh8*)(sA + awoff) = p.v;
  }
  WAITVL(0);
  SBAR(); FENCE();
#pragma unroll
  for (int kk = 0; kk < 2; ++kk) {
    bh8 a = *(const bh8*)(sA + (aro ^ (kk << 6)));
#pragma unroll
    for (int n2 = 0; n2 < 4; ++n2) {
      bh8 bb = *(const bh8*)(sBc + (bro[n2] ^ (kk << 6)));
      acc[n2] = __builtin_amdgcn_mfma_f32_16x16x32_bf16(a, bb, acc[n2], 0, 0, 0);
    }
  }

  float* Z = Zp + (size_t)c * (N_SZ * 128) + (size_t)n0 * 128;
#pragma unroll
  for (int n2 = 0; n2 < 4; ++n2)
#pragma unroll
    for (int q = 0; q < 4; ++q) {
      int r = wr * 16 + l4 * 4 + q;
      int cc = wc * 64 + n2 * 16 + l15;
      Z[r * 128 + cc] = acc[n2][q];
    }

  __threadfence();
  __syncthreads();
  if (t == 0) lastFlag = (atomicAdd(&cnt[nb], 1) == SPLITKZ - 1) ? 1u : 0u;
  __syncthreads();
  if (lastFlag) {
    __threadfence();
    float* ftile = (float*)smem;  // [64][130] f32
    for (int idx = t; idx < 64 * 128; idx += 512) {
      int r = idx >> 7, ccol = idx & 127;
      float v = bd[ccol];
#pragma unroll
      for (int cc = 0; cc < SPLITKZ; ++cc)
        v += Zp[(size_t)cc * (N_SZ * 128) + (size_t)(n0 + r) * 128 + ccol];
      float res = s_src[(size_t)(n0 + r) * 128 + ccol] + fast_tanh(v);
      s_out[(size_t)(n0 + r) * 128 + ccol] = res;
      ftile[r * 130 + ccol] = res;
    }
    __syncthreads();
    for (int idx = t; idx < 64 * 128; idx += 512) {
      int rr = idx & 63, cc = idx >> 6;
      sT[(size_t)cc * 4096 + n0 + rr] = ftile[rr * 130 + cc];
    }
  }
}

// ---------------------------------------------------------------------------
// pB v5: out = act + sum_d tanh(kern @ y_d + b_d). Single 512MB A pass.
// grid 512 (2 blocks/CU -- TLP hides per-iter latency), 512 thr (8 waves,
// wr=wid>>2 x wc=wid&3). Tile 64r x 512tc (4 depths), K-step 32, 128 iters.
// R1's proven 2-barrier counted-vmcnt rhythm. LDS 68KB = sA 4K + sB 2x32K.
// Per iter per thread: 1 A float4 load (reg), 4 B async16. acc 64 f32.
// ---------------------------------------------------------------------------
__global__ __launch_bounds__(512, 2) void pB_kernel(
    const float* __restrict__ A, const u16* __restrict__ Yt,
    const float* __restrict__ act, const float* __restrict__ bias,
    float* __restrict__ outA) {
  __shared__ char smem[4096 + 2 * 32768];
  char* sA = smem;
  char* sB0 = smem + 4096;
  char* sB1 = smem + 4096 + 32768;
  const int t = threadIdx.x, lane = t & 63, wid = t >> 6;
  const int wr = wid >> 2, wc = wid & 3;
  const int m0 = blockIdx.x * 64;
  const int l15 = lane & 15, l4 = lane >> 4;

  // A staging: 64 rows x 32 k f32 = 8KB/iter, 1 float4/thread.
  // thread: row t>>3, seg t&7 (4 floats). sA bf16 row = 64B; 8B write at
  // granule-consistent swizzle: ((seg>>1)^(row&3))*16 + (seg&1)*8.
  const int arow = t >> 3, aseg = t & 7;
  const float4* agp = (const float4*)(A + (size_t)(m0 + arow) * 4096 + aseg * 4);
  const int awoff = arow * 64 + ((((aseg >> 1) ^ (arow & 3))) << 4) + ((aseg & 1) << 3);

  // B staging (R1 pattern): 4 async16/thread, 512tc x 32k bf16 = 32KB/iter.
  const u16* bsrc[4];
  int bldst[4];
#pragma unroll
  for (int j = 0; j < 4; ++j) {
    int P = wid * 256 + j * 64 + lane;
    int col = P >> 2;
    int g = (P & 3) ^ (col & 3);
    bsrc[j] = Yt + (size_t)col * 4096 + g * 8;
    bldst[j] = wid * 4096 + j * 1024;  // wave-uniform
  }

  int aro[2], bro[4][2];
#pragma unroll
  for (int mf = 0; mf < 2; ++mf) {
    int row = wr * 32 + mf * 16 + l15;
    aro[mf] = row * 64 + ((l4 ^ (row & 3)) << 4);
  }
#pragma unroll
  for (int d = 0; d < 4; ++d)
#pragma unroll
    for (int n2 = 0; n2 < 2; ++n2) {
      int cb = d * 128 + wc * 32 + n2 * 16 + l15;
      bro[d][n2] = cb * 64 + ((l4 ^ (cb & 3)) << 4);
    }

  f4 acc[2][4][2];  // [mf][depth][n2] = 64 f32
#pragma unroll
  for (int i = 0; i < 2; ++i)
#pragma unroll
    for (int j = 0; j < 4; ++j)
#pragma unroll
      for (int k = 0; k < 2; ++k) acc[i][j][k] = (f4){0.f, 0.f, 0.f, 0.f};

  // prologue: A(0) 1 load, then B(0) 4 async (FIFO order)
  float4 va = agp[0];
  FENCE();
#pragma unroll
  for (int j = 0; j < 4; ++j) async16(bsrc[j], sB0 + bldst[j]);
  FENCE();

  char* sBc = sB0;
  char* sBn = sB1;
#pragma unroll 1
  for (int k = 0; k < 127; ++k) {
    SBAR(); FENCE();
    WAITV(4);  // drain A(k) reg; B(k) x4 still in flight
    union { ushort4 v; u16 u[4]; } p;
    p.u[0] = f2bf(va.x); p.u[1] = f2bf(va.y); p.u[2] = f2bf(va.z); p.u[3] = f2bf(va.w);
    *(ushort4*)(sA + awoff) = p.v;
    FENCE();
    va = agp[(k + 1) * 8];  // issue A(k+1): +32 floats
    FENCE();
    WAITVL(1);  // drain B(k); A(k+1) stays in flight
    SBAR(); FENCE();
#pragma unroll
    for (int j = 0; j < 4; ++j) async16(bsrc[j] + (k + 1) * 32, sBn + bldst[j]);
    FENCE();
    bh8 af[2];
#pragma unroll
    for (int mf = 0; mf < 2; ++mf) af[mf] = *(const bh8*)(sA + aro[mf]);
#pragma unroll
    for (int d = 0; d < 4; ++d)
#pragma unroll
      for (int n2 = 0; n2 < 2; ++n2) {
        bh8 b = *(const bh8*)(sBc + bro[d][n2]);
#pragma unroll
        for (int mf = 0; mf < 2; ++mf)
          acc[mf][d][n2] =
              __builtin_amdgcn_mfma_f32_16x16x32_bf16(af[mf], b, acc[mf][d][n2], 0, 0, 0);
      }
    char* tp = sBc; sBc = sBn; sBn = tp;
  }
  // peeled last iter (k = 127)
  SBAR(); FENCE();
  WAITV(4);
  {
    union { ushort4 v; u16 u[4]; } p;
    p.u[0] = f2bf(va.x); p.u[1] = f2bf(va.y); p.u[2] = f2bf(va.z); p.u[3] = f2bf(va.w);
    *(ushort4*)(sA + awoff) = p.v;
  }
  WAITVL(0);
  SBAR(); FENCE();
  {
    bh8 af[2];
#pragma unroll
    for (int mf = 0; mf < 2; ++mf) af[mf] = *(const bh8*)(sA + aro[mf]);
#pragma unroll
    for (int d = 0; d < 4; ++d)
#pragma unroll
      for (int n2 = 0; n2 < 2; ++n2) {
        bh8 b = *(const bh8*)(sBc + bro[d][n2]);
#pragma unroll
        for (int mf = 0; mf < 2; ++mf)
          acc[mf][d][n2] =
              __builtin_amdgcn_mfma_f32_16x16x32_bf16(af[mf], b, acc[mf][d][n2], 0, 0, 0);
      }
  }

  float bsv[4][2];
#pragma unroll
  for (int d = 0; d < 4; ++d) {
    bsv[d][0] = bias[d * 128 + wc * 32 + l15];
    bsv[d][1] = bias[d * 128 + wc * 32 + 16 + l15];
  }
#pragma unroll
  for (int mf = 0; mf < 2; ++mf)
#pragma unroll
    for (int q = 0; q < 4; ++q) {
      int r = m0 + wr * 32 + mf * 16 + l4 * 4 + q;
      int c = wc * 32 + l15;
      float s0 = 0.f, s1 = 0.f;
#pragma unroll
      for (int d = 0; d < 4; ++d) {
        s0 += fast_tanh(acc[mf][d][0][q] + bsv[d][0]);
        s1 += fast_tanh(acc[mf][d][1][q] + bsv[d][1]);
      }
      size_t o0 = (size_t)r * 128 + c;
      outA[o0] = act[o0] + s0;
      outA[o0 + 16] = act[o0 + 16] + s1;
    }
}

// ---------------------------------------------------------------------------
extern "C" void kernel_launch(void* const* d_in, const int* in_sizes, int n_in,
                              void* d_out, int out_size, void* d_ws, size_t ws_size,
                              hipStream_t stream) {
  const float* act = (const float*)d_in[0];
  const float* self_act = (const float*)d_in[1];
  const float* kern = (const float*)d_in[2];
  const float* self_kern = (const float*)d_in[3];
  const float* weights = (const float*)d_in[4];
  const float* bias = (const float*)d_in[5];
  float* out = (float*)d_out;
  float* s_out = out + (size_t)M_SZ * 128;

  char* ws = (char*)d_ws;
  u16* Yt = (u16*)ws;                          // [512][4096] bf16, 4 MB
  float* Zp = (float*)(ws + (4u << 20));       // [8][4096][128] f32, 16 MB
  u32* counters = (u32*)(ws + (20u << 20));    // [4][64]
  float* sT = (float*)(ws + (24u << 20));      // [128][4096] f32, 2 MB

  t0_kernel<<<dim3(64, 2), 256, 0, stream>>>(self_act, sT);
  for (int d = 0; d < DEPTHS; ++d) {
    const float* s_src = (d == 0) ? self_act : s_out;
    k1_kernel<<<dim3(64, 8), 256, 0, stream>>>(sT, weights + d * 16384,
                                               Yt + (size_t)d * 128 * 4096,
                                               counters + d * 64);
    k2_kernel<<<dim3(64, SPLITKZ), 512, 0, stream>>>(self_kern,
                                                     Yt + (size_t)d * 128 * 4096,
                                                     Zp, counters + d * 64, s_src, s_out,
                                                     sT, bias + d * 128);
  }
  pB_kernel<<<512, 512, 0, stream>>>(kern, Yt, act, bias, out);
}

// Round 8
// 452.956 us; speedup vs baseline: 1.9285x; 1.9285x over previous
//
#include <hip/hip_runtime.h>

#define M_SZ 32768
#define N_SZ 4096
#define DEPTHS 4
#define SPLITK 8
#define KCH 512  // N_SZ / SPLITK

typedef __attribute__((ext_vector_type(8))) short bh8;   // 8 bf16 (4 VGPR) MFMA frag
typedef __attribute__((ext_vector_type(4))) float f4;    // MFMA accumulator
typedef unsigned short u16;
typedef unsigned int u32;

#define SBAR() __builtin_amdgcn_s_barrier()
#define FENCE() asm volatile("" ::: "memory")
#define WAITV(n) asm volatile("s_waitcnt vmcnt(" #n ")" ::: "memory")
#define WAITVL(n) asm volatile("s_waitcnt vmcnt(" #n ") lgkmcnt(0)" ::: "memory")

__device__ __forceinline__ u16 f2bf(float f) {
  u32 u = __float_as_uint(f);
  u = (u + 0x7FFFu + ((u >> 16) & 1u)) >> 16;  // RNE
  return (u16)u;
}

__device__ __forceinline__ float fast_tanh(float x) {
  float ax = __builtin_fabsf(x);
  float e = __builtin_exp2f(ax * 2.8853900817779268f);  // e^(2|x|)
  float r = 1.0f - 2.0f * __builtin_amdgcn_rcpf(e + 1.0f);
  return __builtin_copysignf(r, x);
}

__device__ __forceinline__ void async16(const void* g, void* l) {
  __builtin_amdgcn_global_load_lds((const __attribute__((address_space(1))) u32*)g,
                                   (__attribute__((address_space(3))) u32*)l, 16, 0, 0);
}

// ---------------------------------------------------------------------------
// K1: y_d[i][n] = sum_k s[n][k] * Wd[i][k]   (write TRANSPOSED [i][n], bf16)
// [R2-exact]
// ---------------------------------------------------------------------------
__global__ void k1_kernel(const float* __restrict__ s, const float* __restrict__ Wd,
                          u16* __restrict__ Ytd) {
  const int n = blockIdx.x * 256 + threadIdx.x;
  const int i0 = blockIdx.y * 8;
  float acc[8] = {0.f, 0.f, 0.f, 0.f, 0.f, 0.f, 0.f, 0.f};
  const float4* srow = (const float4*)(s + (size_t)n * 128);
#pragma unroll 4
  for (int k4 = 0; k4 < 32; ++k4) {
    float4 sv = srow[k4];
#pragma unroll
    for (int ii = 0; ii < 8; ++ii) {
      const float* w = Wd + (i0 + ii) * 128 + k4 * 4;
      acc[ii] = fmaf(sv.x, w[0], acc[ii]);
      acc[ii] = fmaf(sv.y, w[1], acc[ii]);
      acc[ii] = fmaf(sv.z, w[2], acc[ii]);
      acc[ii] = fmaf(sv.w, w[3], acc[ii]);
    }
  }
#pragma unroll
  for (int ii = 0; ii < 8; ++ii)
    Ytd[(size_t)(i0 + ii) * 4096 + n] = f2bf(acc[ii]);
}

// ---------------------------------------------------------------------------
// K2a: split-K partials of self_kernel @ y_d.  [R2-exact]
// ---------------------------------------------------------------------------
__global__ __launch_bounds__(512, 2) void k2a_kernel(
    const float* __restrict__ SK, const u16* __restrict__ Ytd, float* __restrict__ Zp) {
  __shared__ char smem[8192 + 2 * 8192];
  char* sA = smem;
  char* sB0 = smem + 8192;
  char* sB1 = smem + 8192 + 8192;
  const int t = threadIdx.x, lane = t & 63, wid = t >> 6;
  const int wr = wid >> 2, wc = wid & 3;
  const int n0 = blockIdx.x * 128;
  const int kbase = blockIdx.y * KCH;

  const int arow = t >> 2, kseg = t & 3;
  const float4* ag = (const float4*)(SK + (size_t)(n0 + arow) * 4096 + kbase + kseg * 8);
  const int awoff = arow * 64 + ((kseg ^ (arow & 3)) << 4);

  const int P = wid * 64 + lane;
  const int bcol = P >> 2;
  const int bg = (P & 3) ^ (bcol & 3);
  const u16* bsrc = Ytd + (size_t)bcol * 4096 + kbase + bg * 8;
  const int bldst = wid * 1024;  // wave-uniform

  const int l15 = lane & 15, l4 = lane >> 4;
  int aro[4], bro[2];
#pragma unroll
  for (int mf = 0; mf < 4; ++mf) {
    int row = wr * 64 + mf * 16 + l15;
    aro[mf] = row * 64 + ((l4 ^ (row & 3)) << 4);
  }
#pragma unroll
  for (int n2 = 0; n2 < 2; ++n2) {
    int col = wc * 32 + n2 * 16 + l15;
    bro[n2] = col * 64 + ((l4 ^ (col & 3)) << 4);
  }

  f4 acc[4][2];
#pragma unroll
  for (int i = 0; i < 4; ++i)
#pragma unroll
    for (int j = 0; j < 2; ++j) acc[i][j] = (f4){0.f, 0.f, 0.f, 0.f};

  float4 va0 = ag[0], va1 = ag[1];
  FENCE();
  async16(bsrc, sB0 + bldst);
  FENCE();

  char* sBc = sB0;
  char* sBn = sB1;
  for (int k = 0; k < 15; ++k) {
    SBAR(); FENCE();
    WAITV(1);
    union { bh8 v; u16 u[8]; } p;
    p.u[0] = f2bf(va0.x); p.u[1] = f2bf(va0.y); p.u[2] = f2bf(va0.z); p.u[3] = f2bf(va0.w);
    p.u[4] = f2bf(va1.x); p.u[5] = f2bf(va1.y); p.u[6] = f2bf(va1.z); p.u[7] = f2bf(va1.w);
    *(bh8*)(sA + awoff) = p.v;
    FENCE();
    va0 = ag[(k + 1) * 8]; va1 = ag[(k + 1) * 8 + 1];
    FENCE();
    WAITVL(2);
    SBAR(); FENCE();
    async16(bsrc + (k + 1) * 32, sBn + bldst);
    FENCE();
    bh8 af[4];
#pragma unroll
    for (int mf = 0; mf < 4; ++mf) af[mf] = *(const bh8*)(sA + aro[mf]);
#pragma unroll
    for (int n2 = 0; n2 < 2; ++n2) {
      bh8 b = *(const bh8*)(sBc + bro[n2]);
#pragma unroll
      for (int mf = 0; mf < 4; ++mf)
        acc[mf][n2] = __builtin_amdgcn_mfma_f32_16x16x32_bf16(af[mf], b, acc[mf][n2], 0, 0, 0);
    }
    char* tp = sBc; sBc = sBn; sBn = tp;
  }
  SBAR(); FENCE();
  WAITV(1);
  {
    union { bh8 v; u16 u[8]; } p;
    p.u[0] = f2bf(va0.x); p.u[1] = f2bf(va0.y); p.u[2] = f2bf(va0.z); p.u[3] = f2bf(va0.w);
    p.u[4] = f2bf(va1.x); p.u[5] = f2bf(va1.y); p.u[6] = f2bf(va1.z); p.u[7] = f2bf(va1.w);
    *(bh8*)(sA + awoff) = p.v;
  }
  WAITVL(0);
  SBAR(); FENCE();
  {
    bh8 af[4];
#pragma unroll
    for (int mf = 0; mf < 4; ++mf) af[mf] = *(const bh8*)(sA + aro[mf]);
#pragma unroll
    for (int n2 = 0; n2 < 2; ++n2) {
      bh8 b = *(const bh8*)(sBc + bro[n2]);
#pragma unroll
      for (int mf = 0; mf < 4; ++mf)
        acc[mf][n2] = __builtin_amdgcn_mfma_f32_16x16x32_bf16(af[mf], b, acc[mf][n2], 0, 0, 0);
    }
  }

  float* Z = Zp + (size_t)blockIdx.y * (N_SZ * 128) + (size_t)n0 * 128;
#pragma unroll
  for (int mf = 0; mf < 4; ++mf)
#pragma unroll
    for (int n2 = 0; n2 < 2; ++n2)
#pragma unroll
      for (int q = 0; q < 4; ++q) {
        int r = wr * 64 + mf * 16 + l4 * 4 + q;
        int c = wc * 32 + n2 * 16 + l15;
        Z[r * 128 + c] = acc[mf][n2][q];
      }
}

// ---------------------------------------------------------------------------
// K2b: s[n][i] += tanh(sum_c Zp[c][n][i] + b[i])  [R2-exact]
// ---------------------------------------------------------------------------
__global__ void k2b_kernel(float* __restrict__ s, const float* __restrict__ Zp,
                           const float* __restrict__ bd) {
  int idx = blockIdx.x * 256 + threadIdx.x;
  float v = bd[idx & 127];
#pragma unroll
  for (int c = 0; c < SPLITK; ++c) v += Zp[(size_t)c * (N_SZ * 128) + idx];
  s[idx] += fast_tanh(v);
}

// ---------------------------------------------------------------------------
// pB: SPLIT-K-2 version of R1/R2's proven phaseB (same tile, same staging,
// same 2-barrier counted-vmcnt rhythm). grid 512 = 2 blocks/CU (LDS 72KB x2
// = 144KB <= 160KB) so co-resident blocks overlap each other's A/B waits.
// Each block: 128 rows x 512tc (4 depths) over K half [kh*2048, +2048),
// 64 iters, writes pre-activation f32 partials to P[kh].
// ---------------------------------------------------------------------------
__global__ __launch_bounds__(512, 2) void pB_kernel(
    const float* __restrict__ A, const u16* __restrict__ Yt,
    float* __restrict__ P0, float* __restrict__ P1) {
  __shared__ char smem[8192 + 2 * 32768];
  char* sA = smem;
  char* sB0 = smem + 8192;
  char* sB1 = smem + 8192 + 32768;
  const int t = threadIdx.x, lane = t & 63, wid = t >> 6;
  const int wr = wid >> 2, wc = wid & 3;
  const int mb = blockIdx.x & 255, kh = blockIdx.x >> 8;
  const int m0 = mb * 128;
  const int kb = kh * 2048;

  const int arow = t >> 2, kseg = t & 3;
  const float4* ag = (const float4*)(A + (size_t)(m0 + arow) * 4096 + kb + kseg * 8);
  const int awoff = arow * 64 + ((kseg ^ (arow & 3)) << 4);

  const u16* bsrc[4];
  int bldst[4];
#pragma unroll
  for (int j = 0; j < 4; ++j) {
    int P = wid * 256 + j * 64 + lane;
    int col = P >> 2;
    int g = (P & 3) ^ (col & 3);
    bsrc[j] = Yt + (size_t)col * 4096 + kb + g * 8;
    bldst[j] = wid * 4096 + j * 1024;  // wave-uniform
  }

  const int l15 = lane & 15, l4 = lane >> 4;
  int aro[4], bro[4][2];
#pragma unroll
  for (int mf = 0; mf < 4; ++mf) {
    int row = wr * 64 + mf * 16 + l15;
    aro[mf] = row * 64 + ((l4 ^ (row & 3)) << 4);
  }
#pragma unroll
  for (int d = 0; d < 4; ++d)
#pragma unroll
    for (int n2 = 0; n2 < 2; ++n2) {
      int cb = d * 128 + wc * 32 + n2 * 16 + l15;
      bro[d][n2] = cb * 64 + ((l4 ^ (cb & 3)) << 4);
    }

  f4 acc[4][4][2];  // [mf][depth][n2]
#pragma unroll
  for (int i = 0; i < 4; ++i)
#pragma unroll
    for (int j = 0; j < 4; ++j)
#pragma unroll
      for (int k = 0; k < 2; ++k) acc[i][j][k] = (f4){0.f, 0.f, 0.f, 0.f};

  float4 va0 = ag[0], va1 = ag[1];
  FENCE();
#pragma unroll
  for (int j = 0; j < 4; ++j) async16(bsrc[j], sB0 + bldst[j]);
  FENCE();

  char* sBc = sB0;
  char* sBn = sB1;
  for (int k = 0; k < 63; ++k) {
    SBAR(); FENCE();
    WAITV(4);  // A(k) regs ready (4 B(k) may fly)
    union { bh8 v; u16 u[8]; } p;
    p.u[0] = f2bf(va0.x); p.u[1] = f2bf(va0.y); p.u[2] = f2bf(va0.z); p.u[3] = f2bf(va0.w);
    p.u[4] = f2bf(va1.x); p.u[5] = f2bf(va1.y); p.u[6] = f2bf(va1.z); p.u[7] = f2bf(va1.w);
    *(bh8*)(sA + awoff) = p.v;
    FENCE();
    va0 = ag[(k + 1) * 8]; va1 = ag[(k + 1) * 8 + 1];  // issue A(k+1)
    FENCE();
    WAITVL(2);  // B(k) landed + my sA write done (A(k+1) stays in flight)
    SBAR(); FENCE();
#pragma unroll
    for (int j = 0; j < 4; ++j) async16(bsrc[j] + (k + 1) * 32, sBn + bldst[j]);
    FENCE();
    bh8 af[4];
#pragma unroll
    for (int mf = 0; mf < 4; ++mf) af[mf] = *(const bh8*)(sA + aro[mf]);
#pragma unroll
    for (int d = 0; d < 4; ++d)
#pragma unroll
      for (int n2 = 0; n2 < 2; ++n2) {
        bh8 b = *(const bh8*)(sBc + bro[d][n2]);
#pragma unroll
        for (int mf = 0; mf < 4; ++mf)
          acc[mf][d][n2] =
              __builtin_amdgcn_mfma_f32_16x16x32_bf16(af[mf], b, acc[mf][d][n2], 0, 0, 0);
      }
    char* tp = sBc; sBc = sBn; sBn = tp;
  }
  // peeled last iter (k = 63)
  SBAR(); FENCE();
  WAITV(4);
  {
    union { bh8 v; u16 u[8]; } p;
    p.u[0] = f2bf(va0.x); p.u[1] = f2bf(va0.y); p.u[2] = f2bf(va0.z); p.u[3] = f2bf(va0.w);
    p.u[4] = f2bf(va1.x); p.u[5] = f2bf(va1.y); p.u[6] = f2bf(va1.z); p.u[7] = f2bf(va1.w);
    *(bh8*)(sA + awoff) = p.v;
  }
  WAITVL(0);
  SBAR(); FENCE();
  {
    bh8 af[4];
#pragma unroll
    for (int mf = 0; mf < 4; ++mf) af[mf] = *(const bh8*)(sA + aro[mf]);
#pragma unroll
    for (int d = 0; d < 4; ++d)
#pragma unroll
      for (int n2 = 0; n2 < 2; ++n2) {
        bh8 b = *(const bh8*)(sBc + bro[d][n2]);
#pragma unroll
        for (int mf = 0; mf < 4; ++mf)
          acc[mf][d][n2] =
              __builtin_amdgcn_mfma_f32_16x16x32_bf16(af[mf], b, acc[mf][d][n2], 0, 0, 0);
      }
  }

  // write pre-activation partials: P[r][d*128 + c]
  float* P = kh ? P1 : P0;
#pragma unroll
  for (int mf = 0; mf < 4; ++mf)
#pragma unroll
    for (int q = 0; q < 4; ++q) {
      int r = m0 + wr * 64 + mf * 16 + l4 * 4 + q;
#pragma unroll
      for (int d = 0; d < 4; ++d)
#pragma unroll
        for (int n2 = 0; n2 < 2; ++n2) {
          int c512 = d * 128 + wc * 32 + n2 * 16 + l15;
          P[(size_t)r * 512 + c512] = acc[mf][d][n2][q];
        }
    }
}

// ---------------------------------------------------------------------------
// pC: out[r][c] = act[r][c] + sum_d tanh(P0[r][d*128+c] + P1[...] + bias[d*128+c])
// grid 4096 x 256thr: 8 rows/block, one float4 of c per thread.
// ---------------------------------------------------------------------------
__global__ void pC_kernel(const float* __restrict__ act, const float* __restrict__ P0,
                          const float* __restrict__ P1, const float* __restrict__ bias,
                          float* __restrict__ out) {
  const int t = threadIdx.x;
  const int rr = t >> 5, c4 = (t & 31) * 4;
  const size_t r = (size_t)blockIdx.x * 8 + rr;
  float4 a = *(const float4*)(act + r * 128 + c4);
  float4 s = {0.f, 0.f, 0.f, 0.f};
#pragma unroll
  for (int d = 0; d < 4; ++d) {
    float4 p0 = *(const float4*)(P0 + r * 512 + d * 128 + c4);
    float4 p1 = *(const float4*)(P1 + r * 512 + d * 128 + c4);
    float4 b = *(const float4*)(bias + d * 128 + c4);
    s.x += fast_tanh(p0.x + p1.x + b.x);
    s.y += fast_tanh(p0.y + p1.y + b.y);
    s.z += fast_tanh(p0.z + p1.z + b.z);
    s.w += fast_tanh(p0.w + p1.w + b.w);
  }
  float4 o;
  o.x = a.x + s.x; o.y = a.y + s.y; o.z = a.z + s.z; o.w = a.w + s.w;
  *(float4*)(out + r * 128 + c4) = o;
}

// ---------------------------------------------------------------------------
extern "C" void kernel_launch(void* const* d_in, const int* in_sizes, int n_in,
                              void* d_out, int out_size, void* d_ws, size_t ws_size,
                              hipStream_t stream) {
  const float* act = (const float*)d_in[0];
  const float* self_act = (const float*)d_in[1];
  const float* kern = (const float*)d_in[2];
  const float* self_kern = (const float*)d_in[3];
  const float* weights = (const float*)d_in[4];
  const float* bias = (const float*)d_in[5];
  float* out = (float*)d_out;
  float* s_buf = out + (size_t)M_SZ * 128;  // self_act state lives in its output slot

  char* ws = (char*)d_ws;
  u16* Yt = (u16*)ws;                          // [512][4096] bf16, 4 MB
  float* Zp = (float*)(ws + (4u << 20));       // [SPLITK][4096][128] f32, 16 MB
  float* P0 = (float*)(ws + (64u << 20));      // [32768][512] f32, 64 MB
  float* P1 = (float*)(ws + (128u << 20));     // [32768][512] f32, 64 MB

  hipMemcpyAsync(s_buf, self_act, (size_t)N_SZ * 128 * sizeof(float),
                 hipMemcpyDeviceToDevice, stream);

  for (int d = 0; d < DEPTHS; ++d) {
    k1_kernel<<<dim3(16, 16), 256, 0, stream>>>(s_buf, weights + d * 16384,
                                                Yt + (size_t)d * 128 * 4096);
    k2a_kernel<<<dim3(32, SPLITK), 512, 0, stream>>>(self_kern,
                                                     Yt + (size_t)d * 128 * 4096, Zp);
    k2b_kernel<<<2048, 256, 0, stream>>>(s_buf, Zp, bias + d * 128);
  }
  pB_kernel<<<512, 512, 0, stream>>>(kern, Yt, P0, P1);
  pC_kernel<<<4096, 256, 0, stream>>>(act, P0, P1, bias, out);
}

// Round 10
// 371.328 us; speedup vs baseline: 2.3524x; 1.2198x over previous
//
#include <hip/hip_runtime.h>

#define M_SZ 32768
#define N_SZ 4096
#define DEPTHS 4
#define SPLITK 8
#define KCH 512  // N_SZ / SPLITK

typedef __attribute__((ext_vector_type(8))) short bh8;   // 8 bf16 (4 VGPR) MFMA frag
typedef __attribute__((ext_vector_type(4))) float f4;    // MFMA accumulator
typedef unsigned short u16;
typedef unsigned int u32;

#define SBAR() __builtin_amdgcn_s_barrier()
#define FENCE() asm volatile("" ::: "memory")
#define WAITV(n) asm volatile("s_waitcnt vmcnt(" #n ")" ::: "memory")
#define WAITVL(n) asm volatile("s_waitcnt vmcnt(" #n ") lgkmcnt(0)" ::: "memory")

__device__ __forceinline__ u16 f2bf(float f) {
  u32 u = __float_as_uint(f);
  u = (u + 0x7FFFu + ((u >> 16) & 1u)) >> 16;  // RNE
  return (u16)u;
}

__device__ __forceinline__ float fast_tanh(float x) {
  float ax = __builtin_fabsf(x);
  float e = __builtin_exp2f(ax * 2.8853900817779268f);  // e^(2|x|)
  float r = 1.0f - 2.0f * __builtin_amdgcn_rcpf(e + 1.0f);
  return __builtin_copysignf(r, x);
}

__device__ __forceinline__ void async16(const void* g, void* l) {
  __builtin_amdgcn_global_load_lds((const __attribute__((address_space(1))) u32*)g,
                                   (__attribute__((address_space(3))) u32*)l, 16, 0, 0);
}

// ---------------------------------------------------------------------------
// K1: y_d[i][n] = sum_k s[n][k] * Wd[i][k]   (write TRANSPOSED [i][n], bf16)
// [R2-exact]
// ---------------------------------------------------------------------------
__global__ void k1_kernel(const float* __restrict__ s, const float* __restrict__ Wd,
                          u16* __restrict__ Ytd) {
  const int n = blockIdx.x * 256 + threadIdx.x;
  const int i0 = blockIdx.y * 8;
  float acc[8] = {0.f, 0.f, 0.f, 0.f, 0.f, 0.f, 0.f, 0.f};
  const float4* srow = (const float4*)(s + (size_t)n * 128);
#pragma unroll 4
  for (int k4 = 0; k4 < 32; ++k4) {
    float4 sv = srow[k4];
#pragma unroll
    for (int ii = 0; ii < 8; ++ii) {
      const float* w = Wd + (i0 + ii) * 128 + k4 * 4;
      acc[ii] = fmaf(sv.x, w[0], acc[ii]);
      acc[ii] = fmaf(sv.y, w[1], acc[ii]);
      acc[ii] = fmaf(sv.z, w[2], acc[ii]);
      acc[ii] = fmaf(sv.w, w[3], acc[ii]);
    }
  }
#pragma unroll
  for (int ii = 0; ii < 8; ++ii)
    Ytd[(size_t)(i0 + ii) * 4096 + n] = f2bf(acc[ii]);
}

// ---------------------------------------------------------------------------
// K2a: split-K partials of self_kernel @ y_d.  [R2-exact]
// ---------------------------------------------------------------------------
__global__ __launch_bounds__(512, 2) void k2a_kernel(
    const float* __restrict__ SK, const u16* __restrict__ Ytd, float* __restrict__ Zp) {
  __shared__ char smem[8192 + 2 * 8192];
  char* sA = smem;
  char* sB0 = smem + 8192;
  char* sB1 = smem + 8192 + 8192;
  const int t = threadIdx.x, lane = t & 63, wid = t >> 6;
  const int wr = wid >> 2, wc = wid & 3;
  const int n0 = blockIdx.x * 128;
  const int kbase = blockIdx.y * KCH;

  const int arow = t >> 2, kseg = t & 3;
  const float4* ag = (const float4*)(SK + (size_t)(n0 + arow) * 4096 + kbase + kseg * 8);
  const int awoff = arow * 64 + ((kseg ^ (arow & 3)) << 4);

  const int P = wid * 64 + lane;
  const int bcol = P >> 2;
  const int bg = (P & 3) ^ (bcol & 3);
  const u16* bsrc = Ytd + (size_t)bcol * 4096 + kbase + bg * 8;
  const int bldst = wid * 1024;  // wave-uniform

  const int l15 = lane & 15, l4 = lane >> 4;
  int aro[4], bro[2];
#pragma unroll
  for (int mf = 0; mf < 4; ++mf) {
    int row = wr * 64 + mf * 16 + l15;
    aro[mf] = row * 64 + ((l4 ^ (row & 3)) << 4);
  }
#pragma unroll
  for (int n2 = 0; n2 < 2; ++n2) {
    int col = wc * 32 + n2 * 16 + l15;
    bro[n2] = col * 64 + ((l4 ^ (col & 3)) << 4);
  }

  f4 acc[4][2];
#pragma unroll
  for (int i = 0; i < 4; ++i)
#pragma unroll
    for (int j = 0; j < 2; ++j) acc[i][j] = (f4){0.f, 0.f, 0.f, 0.f};

  float4 va0 = ag[0], va1 = ag[1];
  FENCE();
  async16(bsrc, sB0 + bldst);
  FENCE();

  char* sBc = sB0;
  char* sBn = sB1;
  for (int k = 0; k < 15; ++k) {
    SBAR(); FENCE();
    WAITV(1);
    union { bh8 v; u16 u[8]; } p;
    p.u[0] = f2bf(va0.x); p.u[1] = f2bf(va0.y); p.u[2] = f2bf(va0.z); p.u[3] = f2bf(va0.w);
    p.u[4] = f2bf(va1.x); p.u[5] = f2bf(va1.y); p.u[6] = f2bf(va1.z); p.u[7] = f2bf(va1.w);
    *(bh8*)(sA + awoff) = p.v;
    FENCE();
    va0 = ag[(k + 1) * 8]; va1 = ag[(k + 1) * 8 + 1];
    FENCE();
    WAITVL(2);
    SBAR(); FENCE();
    async16(bsrc + (k + 1) * 32, sBn + bldst);
    FENCE();
    bh8 af[4];
#pragma unroll
    for (int mf = 0; mf < 4; ++mf) af[mf] = *(const bh8*)(sA + aro[mf]);
#pragma unroll
    for (int n2 = 0; n2 < 2; ++n2) {
      bh8 b = *(const bh8*)(sBc + bro[n2]);
#pragma unroll
      for (int mf = 0; mf < 4; ++mf)
        acc[mf][n2] = __builtin_amdgcn_mfma_f32_16x16x32_bf16(af[mf], b, acc[mf][n2], 0, 0, 0);
    }
    char* tp = sBc; sBc = sBn; sBn = tp;
  }
  SBAR(); FENCE();
  WAITV(1);
  {
    union { bh8 v; u16 u[8]; } p;
    p.u[0] = f2bf(va0.x); p.u[1] = f2bf(va0.y); p.u[2] = f2bf(va0.z); p.u[3] = f2bf(va0.w);
    p.u[4] = f2bf(va1.x); p.u[5] = f2bf(va1.y); p.u[6] = f2bf(va1.z); p.u[7] = f2bf(va1.w);
    *(bh8*)(sA + awoff) = p.v;
  }
  WAITVL(0);
  SBAR(); FENCE();
  {
    bh8 af[4];
#pragma unroll
    for (int mf = 0; mf < 4; ++mf) af[mf] = *(const bh8*)(sA + aro[mf]);
#pragma unroll
    for (int n2 = 0; n2 < 2; ++n2) {
      bh8 b = *(const bh8*)(sBc + bro[n2]);
#pragma unroll
      for (int mf = 0; mf < 4; ++mf)
        acc[mf][n2] = __builtin_amdgcn_mfma_f32_16x16x32_bf16(af[mf], b, acc[mf][n2], 0, 0, 0);
    }
  }

  float* Z = Zp + (size_t)blockIdx.y * (N_SZ * 128) + (size_t)n0 * 128;
#pragma unroll
  for (int mf = 0; mf < 4; ++mf)
#pragma unroll
    for (int n2 = 0; n2 < 2; ++n2)
#pragma unroll
      for (int q = 0; q < 4; ++q) {
        int r = wr * 64 + mf * 16 + l4 * 4 + q;
        int c = wc * 32 + n2 * 16 + l15;
        Z[r * 128 + c] = acc[mf][n2][q];
      }
}

// ---------------------------------------------------------------------------
// K2b: s[n][i] += tanh(sum_c Zp[c][n][i] + b[i])  [R2-exact]
// ---------------------------------------------------------------------------
__global__ void k2b_kernel(float* __restrict__ s, const float* __restrict__ Zp,
                           const float* __restrict__ bd) {
  int idx = blockIdx.x * 256 + threadIdx.x;
  float v = bd[idx & 127];
#pragma unroll
  for (int c = 0; c < SPLITK; ++c) v += Zp[(size_t)c * (N_SZ * 128) + idx];
  s[idx] += fast_tanh(v);
}

// ---------------------------------------------------------------------------
// phaseB v6b: out = act + sum_d tanh(kern @ y_d + b_d). Single 512MB A pass,
// direct output. grid 256, block 1024 (16 waves = 4/SIMD intra-block TLP).
// Tile 128r x 512tc, K-step 32, 128 iters.
// Wave decomposition (FIXED from R9's OOB bug): wr = wid>>3 in {0,1},
// wc = wid&7 in {0..7}. Wave owns rows [wr*64, wr*64+64) via mf*16, and
// cols [wc*16, wc*16+16) of EACH depth d. acc[4 mf][4 d] = 64 f32.
// Range check: row = wr*64+mf*16+l15 <= 127; aro <= 8191; tc <= 511;
// epilogue r <= m0+127. All in bounds.
// Per thread/iter: 1 A float4 -> 8B sA write, 2 async16 B, 8 ds_read_b128.
// Same 2-barrier counted-vmcnt rhythm and XOR-swizzle algebra as R2.
// ---------------------------------------------------------------------------
__global__ __launch_bounds__(1024, 4) void pB_kernel(
    const float* __restrict__ A, const u16* __restrict__ Yt,
    const float* __restrict__ act, const float* __restrict__ bias,
    float* __restrict__ outA) {
  __shared__ char smem[8192 + 2 * 32768];
  char* sA = smem;
  char* sB0 = smem + 8192;
  char* sB1 = smem + 8192 + 32768;
  const int t = threadIdx.x, lane = t & 63, wid = t >> 6;
  const int wr = wid >> 3, wc = wid & 7;
  const int m0 = blockIdx.x * 128;
  const int l15 = lane & 15, l4 = lane >> 4;

  // A staging: 128 rows x 32 k f32 (16KB src) -> 1 float4/thread -> 8B bf16.
  // row = t>>3, aseg = t&7 (4-float source granule). 16B-slot XOR swizzle
  // slot = (aseg>>1)^(row&3), half = aseg&1  (matches read algebra below).
  const int arow = t >> 3, aseg = t & 7;
  const float4* agp = (const float4*)(A + (size_t)(m0 + arow) * 4096 + aseg * 4);
  const int awoff = arow * 64 + (((aseg >> 1) ^ (arow & 3)) << 4) + ((aseg & 1) << 3);

  // B staging: 512 cols x 32 k bf16 (32KB) -> 2 async16/thread.
  const u16* bsrc[2];
  int bldst[2];
#pragma unroll
  for (int j = 0; j < 2; ++j) {
    int G = j * 1024 + t;
    int col = G >> 2;
    int g = (G & 3) ^ (col & 3);
    bsrc[j] = Yt + (size_t)col * 4096 + g * 8;
    bldst[j] = (j * 16 + wid) * 1024;  // wave-uniform base (+ lane*16 by HW)
  }

  // consume offsets
  int aro[4], bro[4];
#pragma unroll
  for (int mf = 0; mf < 4; ++mf) {
    int row = wr * 64 + mf * 16 + l15;  // in [0,128) exactly once over (wr,mf)
    aro[mf] = row * 64 + ((l4 ^ (row & 3)) << 4);
  }
#pragma unroll
  for (int d = 0; d < 4; ++d) {
    int tc = d * 128 + wc * 16 + l15;   // in [0,512)
    bro[d] = tc * 64 + ((l4 ^ (tc & 3)) << 4);
  }

  f4 acc[4][4];  // [mf][d] -- 64 f32
#pragma unroll
  for (int i = 0; i < 4; ++i)
#pragma unroll
    for (int j = 0; j < 4; ++j) acc[i][j] = (f4){0.f, 0.f, 0.f, 0.f};

  // prologue: A(0), then B(0) x2 (FIFO order)
  float4 va = agp[0];
  FENCE();
  async16(bsrc[0], sB0 + bldst[0]);
  async16(bsrc[1], sB0 + bldst[1]);
  FENCE();

  char* sBc = sB0;
  char* sBn = sB1;
#pragma unroll 1
  for (int k = 0; k < 127; ++k) {
    SBAR(); FENCE();
    WAITV(2);  // retire A(k); B(k) x2 may fly
    union { uint2 v; u16 u[4]; } p;
    p.u[0] = f2bf(va.x); p.u[1] = f2bf(va.y); p.u[2] = f2bf(va.z); p.u[3] = f2bf(va.w);
    *(uint2*)(sA + awoff) = p.v;
    FENCE();
    va = agp[(k + 1) * 8];  // issue A(k+1)
    FENCE();
    WAITVL(1);  // retire B(k) x2; A(k+1) stays in flight
    SBAR(); FENCE();
    async16(bsrc[0] + (k + 1) * 32, sBn + bldst[0]);
    async16(bsrc[1] + (k + 1) * 32, sBn + bldst[1]);
    FENCE();
    bh8 af[4];
#pragma unroll
    for (int mf = 0; mf < 4; ++mf) af[mf] = *(const bh8*)(sA + aro[mf]);
#pragma unroll
    for (int d = 0; d < 4; ++d) {
      bh8 b = *(const bh8*)(sBc + bro[d]);
#pragma unroll
      for (int mf = 0; mf < 4; ++mf)
        acc[mf][d] = __builtin_amdgcn_mfma_f32_16x16x32_bf16(af[mf], b, acc[mf][d], 0, 0, 0);
    }
    char* tp = sBc; sBc = sBn; sBn = tp;
  }
  // peeled last iter (k = 127)
  SBAR(); FENCE();
  WAITV(2);
  {
    union { uint2 v; u16 u[4]; } p;
    p.u[0] = f2bf(va.x); p.u[1] = f2bf(va.y); p.u[2] = f2bf(va.z); p.u[3] = f2bf(va.w);
    *(uint2*)(sA + awoff) = p.v;
  }
  WAITVL(0);
  SBAR(); FENCE();
  {
    bh8 af[4];
#pragma unroll
    for (int mf = 0; mf < 4; ++mf) af[mf] = *(const bh8*)(sA + aro[mf]);
#pragma unroll
    for (int d = 0; d < 4; ++d) {
      bh8 b = *(const bh8*)(sBc + bro[d]);
#pragma unroll
      for (int mf = 0; mf < 4; ++mf)
        acc[mf][d] = __builtin_amdgcn_mfma_f32_16x16x32_bf16(af[mf], b, acc[mf][d], 0, 0, 0);
    }
  }

  float bsv[4];
#pragma unroll
  for (int d = 0; d < 4; ++d) bsv[d] = bias[d * 128 + wc * 16 + l15];
#pragma unroll
  for (int mf = 0; mf < 4; ++mf)
#pragma unroll
    for (int q = 0; q < 4; ++q) {
      int r = m0 + wr * 64 + mf * 16 + l4 * 4 + q;  // <= m0 + 127
      int c = wc * 16 + l15;
      float s = 0.f;
#pragma unroll
      for (int d = 0; d < 4; ++d) s += fast_tanh(acc[mf][d][q] + bsv[d]);
      size_t o = (size_t)r * 128 + c;
      outA[o] = act[o] + s;
    }
}

// ---------------------------------------------------------------------------
extern "C" void kernel_launch(void* const* d_in, const int* in_sizes, int n_in,
                              void* d_out, int out_size, void* d_ws, size_t ws_size,
                              hipStream_t stream) {
  const float* act = (const float*)d_in[0];
  const float* self_act = (const float*)d_in[1];
  const float* kern = (const float*)d_in[2];
  const float* self_kern = (const float*)d_in[3];
  const float* weights = (const float*)d_in[4];
  const float* bias = (const float*)d_in[5];
  float* out = (float*)d_out;
  float* s_buf = out + (size_t)M_SZ * 128;  // self_act state lives in its output slot

  char* ws = (char*)d_ws;
  u16* Yt = (u16*)ws;                          // [512][4096] bf16, 4 MB
  float* Zp = (float*)(ws + (4u << 20));       // [SPLITK][4096][128] f32, 16 MB

  hipMemcpyAsync(s_buf, self_act, (size_t)N_SZ * 128 * sizeof(float),
                 hipMemcpyDeviceToDevice, stream);

  for (int d = 0; d < DEPTHS; ++d) {
    k1_kernel<<<dim3(16, 16), 256, 0, stream>>>(s_buf, weights + d * 16384,
                                                Yt + (size_t)d * 128 * 4096);
    k2a_kernel<<<dim3(32, SPLITK), 512, 0, stream>>>(self_kern,
                                                     Yt + (size_t)d * 128 * 4096, Zp);
    k2b_kernel<<<2048, 256, 0, stream>>>(s_buf, Zp, bias + d * 128);
  }
  pB_kernel<<<256, 1024, 0, stream>>>(kern, Yt, act, bias, out);
}